// Round 9
// baseline (2520.832 us; speedup 1.0000x reference)
//
#include <hip/hip_runtime.h>
#include <hip/hip_fp16.h>

// CapsNet dynamic routing, B=256, P=2048, C=10, OUT=16, IN=8, 3 iters.
// R9: NO materialized u_hat. Each routing pass recomputes u_hat[b,p,c,o]
// from u,W on the fly (48 FLOP per elem over 3 passes vs 8 bytes of HBM
// traffic for the stored version -> 4x cheaper on the roofline, and W+u
// are L2/L3-resident). Pipeline:
//   k_init: zero s-accumulators (ws is poisoned 0xAA every launch)
//   k_pass<1>: s1 = sum_p u_hat           (c uniform; 0.1 applied in k_sq)
//   k_sq<0>:  v1 = squash(0.1*s1) -> fp16
//   k_pass<2>: s2 = sum_p softmax_c(uh.v1) uh
//   k_sq<1>:  v12 = v1 + squash(s2) -> fp16   (pass-3 logits = uh.(v1+v2))
//   k_pass<2>: s3 with v12
//   k_fin:    out = squash(s3)
// Pass kernel: grid 512 (2 blocks/CU), TPB 256, thread=(b, c-half h).
// W loads: all lanes of a pair share addresses -> L1 dedup; u contiguous
// per thread over its 8-p slice. Cross-block s reduce: global fp32 atomics.

#define Bn 256
#define Pn 2048
#define Cn 10
#define On 16
#define In 8
#define ROW 160
#define HROW 80
#define PSL 8            // p's per slice (256 slices)

typedef _Float16 h2f __attribute__((ext_vector_type(2)));
union LV { float4 f; h2f e[4]; };

__device__ __forceinline__ h2f pack2(float a, float b) {
  __half2 t = __floats2half2_rn(a, b);
  return *reinterpret_cast<h2f*>(&t);
}
__device__ __forceinline__ float2 unpack2(h2f x) {
  return __half22float2(*reinterpret_cast<__half2*>(&x));
}

// ---------------- k_init: zero g_s1/2/3 (122880 floats) ----------------
__global__ __launch_bounds__(256) void k_init(float4* __restrict__ gs) {
  gs[blockIdx.x * 256 + threadIdx.x] = float4{0.f, 0.f, 0.f, 0.f};
}

// ---------------- pass kernel ----------------
template <int PHASE>
__global__ __launch_bounds__(256, 2) void k_pass(const float* __restrict__ u,
                                                 const float* __restrict__ W,
                                                 const __half* __restrict__ vin,
                                                 float* __restrict__ gout) {
  const int x = blockIdx.x;
  const int slice = x & 255;        // same-slice pair x, x+256: same XCD
  const int b0 = (x >> 8) * 128;
  const int tid = threadIdx.x;
  const int h = tid & 1;
  const int b = b0 + (tid >> 1);
  const int p0 = slice * PSL;

  h2f vh[5][8];
  if (PHASE >= 2) {
    const float4* vp4 =
        reinterpret_cast<const float4*>(vin + ((size_t)b * 2 + h) * HROW);
#pragma unroll
    for (int kc = 0; kc < 5; ++kc) {
      LV a, c;
      a.f = vp4[kc * 2];
      c.f = vp4[kc * 2 + 1];
#pragma unroll
      for (int q = 0; q < 4; ++q) {
        vh[kc][q] = a.e[q];
        vh[kc][4 + q] = c.e[q];
      }
    }
  }

  float acc[5][16];
#pragma unroll
  for (int kc = 0; kc < 5; ++kc)
#pragma unroll
    for (int o = 0; o < On; ++o) acc[kc][o] = 0.f;

  for (int pi = 0; pi < PSL; ++pi) {
    const int p = p0 + pi;
    const float4* up = reinterpret_cast<const float4*>(u + ((size_t)b * Pn + p) * In);
    float4 ua = up[0], ub = up[1];
    const float uu[8] = {ua.x, ua.y, ua.z, ua.w, ub.x, ub.y, ub.z, ub.w};
    const float* wr = W + (size_t)p * (Cn * On * In) + h * (5 * On * In);

    h2f uhh[5][8]; // this (b,p,h)'s 80 u_hat cells, fp16-packed
#pragma unroll
    for (int kc = 0; kc < 5; ++kc) {
#pragma unroll
      for (int o2 = 0; o2 < 8; ++o2) {
        const float* w0 = wr + (kc * On + 2 * o2) * In;
        float4 wa = *reinterpret_cast<const float4*>(w0);
        float4 wb = *reinterpret_cast<const float4*>(w0 + 4);
        float4 wc = *reinterpret_cast<const float4*>(w0 + 8);
        float4 wd = *reinterpret_cast<const float4*>(w0 + 12);
        float d0 = wa.x * uu[0];
        d0 = __builtin_fmaf(wa.y, uu[1], d0);
        d0 = __builtin_fmaf(wa.z, uu[2], d0);
        d0 = __builtin_fmaf(wa.w, uu[3], d0);
        d0 = __builtin_fmaf(wb.x, uu[4], d0);
        d0 = __builtin_fmaf(wb.y, uu[5], d0);
        d0 = __builtin_fmaf(wb.z, uu[6], d0);
        d0 = __builtin_fmaf(wb.w, uu[7], d0);
        float d1 = wc.x * uu[0];
        d1 = __builtin_fmaf(wc.y, uu[1], d1);
        d1 = __builtin_fmaf(wc.z, uu[2], d1);
        d1 = __builtin_fmaf(wc.w, uu[3], d1);
        d1 = __builtin_fmaf(wd.x, uu[4], d1);
        d1 = __builtin_fmaf(wd.y, uu[5], d1);
        d1 = __builtin_fmaf(wd.z, uu[6], d1);
        d1 = __builtin_fmaf(wd.w, uu[7], d1);
        uhh[kc][o2] = pack2(d0, d1);
      }
    }

    float cv[5];
    if (PHASE == 1) {
#pragma unroll
      for (int kc = 0; kc < 5; ++kc) cv[kc] = 1.f; // 0.1 applied in k_sq
    } else {
      float lg[5];
#pragma unroll
      for (int kc = 0; kc < 5; ++kc) {
        float d = 0.f;
#pragma unroll
        for (int o2 = 0; o2 < 8; ++o2)
          d = __builtin_amdgcn_fdot2(uhh[kc][o2], vh[kc][o2], d, false);
        lg[kc] = d;
      }
      float m = lg[0];
#pragma unroll
      for (int kc = 1; kc < 5; ++kc) m = fmaxf(m, lg[kc]);
      m = fmaxf(m, __shfl_xor(m, 1, 64)); // partner = other c-half, same b
      float e[5], ssum = 0.f;
#pragma unroll
      for (int kc = 0; kc < 5; ++kc) {
        e[kc] = __expf(lg[kc] - m);
        ssum += e[kc];
      }
      ssum += __shfl_xor(ssum, 1, 64);
      const float inv = 1.f / ssum;
#pragma unroll
      for (int kc = 0; kc < 5; ++kc) cv[kc] = e[kc] * inv;
    }
#pragma unroll
    for (int kc = 0; kc < 5; ++kc)
#pragma unroll
      for (int o2 = 0; o2 < 8; ++o2) {
        float2 f = unpack2(uhh[kc][o2]);
        acc[kc][2 * o2] = __builtin_fmaf(cv[kc], f.x, acc[kc][2 * o2]);
        acc[kc][2 * o2 + 1] = __builtin_fmaf(cv[kc], f.y, acc[kc][2 * o2 + 1]);
      }
  }

  float* gp = gout + ((size_t)b * 2 + h) * HROW; // == [b][c(=h*5+kc)][o]
#pragma unroll
  for (int k = 0; k < HROW; ++k) atomicAdd(&gp[k], acc[k >> 4][k & 15]);
}

// ---------------- squash kernels ----------------
template <int ADDPREV>
__global__ __launch_bounds__(256) void k_sq(const float* __restrict__ gs,
                                            const __half* __restrict__ vprev,
                                            __half* __restrict__ vout,
                                            float scale) {
  __shared__ float s[ROW];
  __shared__ float scl[Cn];
  const int b = blockIdx.x, t = threadIdx.x;
  if (t < ROW) s[t] = scale * gs[(size_t)b * ROW + t];
  __syncthreads();
  if (t < Cn) {
    float sq = 0.f;
#pragma unroll
    for (int o = 0; o < On; ++o) { float xv = s[t * On + o]; sq += xv * xv; }
    scl[t] = (sq / (1.f + sq)) / sqrtf(sq + 1e-9f);
  }
  __syncthreads();
  if (t < ROW) {
    float vv = s[t] * scl[t >> 4];
    if (ADDPREV) vv += __half2float(vprev[(size_t)b * ROW + t]);
    vout[(size_t)b * ROW + t] = __float2half(vv);
  }
}

__global__ __launch_bounds__(256) void k_fin(const float* __restrict__ gs,
                                             float* __restrict__ out) {
  __shared__ float s[ROW];
  __shared__ float scl[Cn];
  const int b = blockIdx.x, t = threadIdx.x;
  if (t < ROW) s[t] = gs[(size_t)b * ROW + t];
  __syncthreads();
  if (t < Cn) {
    float sq = 0.f;
#pragma unroll
    for (int o = 0; o < On; ++o) { float xv = s[t * On + o]; sq += xv * xv; }
    scl[t] = (sq / (1.f + sq)) / sqrtf(sq + 1e-9f);
  }
  __syncthreads();
  if (t < ROW) out[(size_t)b * ROW + t] = s[t] * scl[t >> 4];
}

extern "C" void kernel_launch(void* const* d_in, const int* in_sizes, int n_in,
                              void* d_out, int out_size, void* d_ws, size_t ws_size,
                              hipStream_t stream) {
  (void)in_sizes; (void)n_in; (void)out_size;
  const float* u = (const float*)d_in[0];
  const float* W = (const float*)d_in[1];
  float* out = (float*)d_out;
  const size_t SB = (size_t)Bn * ROW; // 40960
  float* g_s1 = (float*)d_ws;
  float* g_s2 = g_s1 + SB;
  float* g_s3 = g_s2 + SB;
  __half* g_v1 = (__half*)(g_s3 + SB);
  __half* g_v12 = g_v1 + SB;
  if (ws_size < 3 * SB * sizeof(float) + 2 * SB * sizeof(__half)) return;

  k_init<<<120, 256, 0, stream>>>((float4*)g_s1); // zeroes s1,s2,s3 exactly
  k_pass<1><<<512, 256, 0, stream>>>(u, W, nullptr, g_s1);
  k_sq<0><<<Bn, 256, 0, stream>>>(g_s1, nullptr, g_v1, 0.1f);
  k_pass<2><<<512, 256, 0, stream>>>(u, W, g_v1, g_s2);
  k_sq<1><<<Bn, 256, 0, stream>>>(g_s2, g_v1, g_v12, 1.0f);
  k_pass<2><<<512, 256, 0, stream>>>(u, W, g_v12, g_s3);
  k_fin<<<Bn, 256, 0, stream>>>(g_s3, out);
}

// Round 10
// 484.406 us; speedup vs baseline: 5.2040x; 5.2040x over previous
//
#include <hip/hip_runtime.h>
#include <hip/hip_fp16.h>

// CapsNet dynamic routing, B=256, P=2048, C=10, OUT=16, IN=8, 3 iters.
// R10: recompute-u_hat passes (R9 idea — FETCH was 13MB, inputs cache-
// resident) with per-thread state cut from ~190 to ~60 regs so the backend
// doesn't spill (R9: TPB=256 budget=60 VGPR -> 327MB scratch -> 790us/pass).
// Proven config everywhere: TPB=512 + launch_bounds(512,2) (only config
// that never spilled: R3/R6/R7/R8 all VGPR 84-100, WRITE clean).
// Decomposition: lane=(b_loc 8, o-pair 8). Per thread: uh0/uh1[10] fp32
// (transient) + acc0/acc1[10]. v via LDS (stride 168 -> only free 2-way
// bank aliasing). Logit dot: 3 shfl_xor over op-lanes; softmax in-thread
// (each lane holds all 10 c). Pass3 logits = uh.(v1+v2) -> no logit buf.
// Block = 8 b x 64 p; grid 1024 = bg*32+slice so same-slice blocks sit on
// one XCD (stride 32) -> W slice L2-resident. s-reduce: LDS atomics then
// ~1280 global atomics/block into g_s (zeroed by k_init; ws is re-poisoned
// 0xAA before every launch).

#define Bn 256
#define Pn 2048
#define Cn 10
#define On 16
#define In 8
#define ROW 160
#define VP 168 // padded LDS row stride (words)

// ---------------- k_init: zero g_s1/2/3 (122880 floats) ----------------
__global__ __launch_bounds__(256) void k_init(float4* __restrict__ gs) {
  gs[blockIdx.x * 256 + threadIdx.x] = float4{0.f, 0.f, 0.f, 0.f};
}

// ---------------- pass kernel ----------------
template <int PHASE>
__global__ __launch_bounds__(512, 2) void k_pass(const float* __restrict__ u,
                                                 const float* __restrict__ W,
                                                 const float* __restrict__ vin,
                                                 float* __restrict__ gout) {
  __shared__ float v_lds[8][VP];
  __shared__ float s_red[8][VP];
  const int x = blockIdx.x;
  const int slice = x & 31; // same-slice blocks: stride 32 -> same XCD
  const int bg = x >> 5;
  const int b0 = bg * 8;
  const int tid = threadIdx.x;
  const int w = tid >> 6;
  const int lane = tid & 63;
  const int bl = lane & 7;  // b within group
  const int op = lane >> 3; // o-pair
  const int b = b0 + bl;
  const int p0 = slice * 64 + w * 8;

  if (PHASE >= 2) {
    for (int i = tid; i < 8 * ROW; i += 512) {
      const int bb = i / ROW, k = i - bb * ROW;
      v_lds[bb][k] = vin[(size_t)(b0 + bb) * ROW + k];
    }
  }
  for (int i = tid; i < 8 * VP; i += 512) (&s_red[0][0])[i] = 0.f;
  __syncthreads();

  float acc0[Cn], acc1[Cn];
#pragma unroll
  for (int c = 0; c < Cn; ++c) { acc0[c] = 0.f; acc1[c] = 0.f; }

  for (int pi = 0; pi < 8; ++pi) {
    const int p = p0 + pi;
    const float4* up = reinterpret_cast<const float4*>(u + ((size_t)b * Pn + p) * In);
    float4 ua = up[0], ub = up[1];
    const float uu[8] = {ua.x, ua.y, ua.z, ua.w, ub.x, ub.y, ub.z, ub.w};
    const float* wr = W + (size_t)p * (Cn * On * In) + op * 16; // (c*16+op*2)*8

    float uh0[Cn], uh1[Cn];
#pragma unroll
    for (int c = 0; c < Cn; ++c) {
      const float* wc_ = wr + c * 128;
      float4 wa = *reinterpret_cast<const float4*>(wc_);
      float4 wb = *reinterpret_cast<const float4*>(wc_ + 4);
      float4 wcc = *reinterpret_cast<const float4*>(wc_ + 8);
      float4 wd = *reinterpret_cast<const float4*>(wc_ + 12);
      float d0 = wa.x * uu[0];
      d0 = __builtin_fmaf(wa.y, uu[1], d0);
      d0 = __builtin_fmaf(wa.z, uu[2], d0);
      d0 = __builtin_fmaf(wa.w, uu[3], d0);
      d0 = __builtin_fmaf(wb.x, uu[4], d0);
      d0 = __builtin_fmaf(wb.y, uu[5], d0);
      d0 = __builtin_fmaf(wb.z, uu[6], d0);
      d0 = __builtin_fmaf(wb.w, uu[7], d0);
      float d1 = wcc.x * uu[0];
      d1 = __builtin_fmaf(wcc.y, uu[1], d1);
      d1 = __builtin_fmaf(wcc.z, uu[2], d1);
      d1 = __builtin_fmaf(wcc.w, uu[3], d1);
      d1 = __builtin_fmaf(wd.x, uu[4], d1);
      d1 = __builtin_fmaf(wd.y, uu[5], d1);
      d1 = __builtin_fmaf(wd.z, uu[6], d1);
      d1 = __builtin_fmaf(wd.w, uu[7], d1);
      uh0[c] = d0;
      uh1[c] = d1;
    }

    float cv[Cn];
    if (PHASE == 1) {
#pragma unroll
      for (int c = 0; c < Cn; ++c) cv[c] = 1.f; // 0.1 applied in k_sq
    } else {
      float lg[Cn];
#pragma unroll
      for (int c = 0; c < Cn; ++c)
        lg[c] = __builtin_fmaf(uh0[c], v_lds[bl][c * On + op * 2],
                               uh1[c] * v_lds[bl][c * On + op * 2 + 1]);
#pragma unroll
      for (int c = 0; c < Cn; ++c) { // reduce over the 8 op-lanes (bits 3-5)
        lg[c] += __shfl_xor(lg[c], 8, 64);
        lg[c] += __shfl_xor(lg[c], 16, 64);
        lg[c] += __shfl_xor(lg[c], 32, 64);
      }
      float m = lg[0];
#pragma unroll
      for (int c = 1; c < Cn; ++c) m = fmaxf(m, lg[c]);
      float e[Cn], ssum = 0.f;
#pragma unroll
      for (int c = 0; c < Cn; ++c) { e[c] = __expf(lg[c] - m); ssum += e[c]; }
      const float inv = 1.f / ssum;
#pragma unroll
      for (int c = 0; c < Cn; ++c) cv[c] = e[c] * inv;
    }
#pragma unroll
    for (int c = 0; c < Cn; ++c) {
      acc0[c] = __builtin_fmaf(cv[c], uh0[c], acc0[c]);
      acc1[c] = __builtin_fmaf(cv[c], uh1[c], acc1[c]);
    }
  }

  // LDS reduce: distinct addrs per lane; across waves atomics serialize
#pragma unroll
  for (int c = 0; c < Cn; ++c) {
    atomicAdd(&s_red[bl][c * On + op * 2], acc0[c]);
    atomicAdd(&s_red[bl][c * On + op * 2 + 1], acc1[c]);
  }
  __syncthreads();
  for (int i = tid; i < 8 * ROW; i += 512) {
    const int bb = i / ROW, k = i - bb * ROW;
    atomicAdd(&gout[(size_t)(b0 + bb) * ROW + k], s_red[bb][k]);
  }
}

// ---------------- squash kernels (fp32 v) ----------------
template <int ADDPREV>
__global__ __launch_bounds__(256) void k_sq(const float* __restrict__ gs,
                                            const float* __restrict__ vprev,
                                            float* __restrict__ vout,
                                            float scale) {
  __shared__ float s[ROW];
  __shared__ float scl[Cn];
  const int b = blockIdx.x, t = threadIdx.x;
  if (t < ROW) s[t] = scale * gs[(size_t)b * ROW + t];
  __syncthreads();
  if (t < Cn) {
    float sq = 0.f;
#pragma unroll
    for (int o = 0; o < On; ++o) { float xv = s[t * On + o]; sq += xv * xv; }
    scl[t] = (sq / (1.f + sq)) / sqrtf(sq + 1e-9f);
  }
  __syncthreads();
  if (t < ROW) {
    float vv = s[t] * scl[t >> 4];
    if (ADDPREV) vv += vprev[(size_t)b * ROW + t];
    vout[(size_t)b * ROW + t] = vv;
  }
}

__global__ __launch_bounds__(256) void k_fin(const float* __restrict__ gs,
                                             float* __restrict__ out) {
  __shared__ float s[ROW];
  __shared__ float scl[Cn];
  const int b = blockIdx.x, t = threadIdx.x;
  if (t < ROW) s[t] = gs[(size_t)b * ROW + t];
  __syncthreads();
  if (t < Cn) {
    float sq = 0.f;
#pragma unroll
    for (int o = 0; o < On; ++o) { float xv = s[t * On + o]; sq += xv * xv; }
    scl[t] = (sq / (1.f + sq)) / sqrtf(sq + 1e-9f);
  }
  __syncthreads();
  if (t < ROW) out[(size_t)b * ROW + t] = s[t] * scl[t >> 4];
}

extern "C" void kernel_launch(void* const* d_in, const int* in_sizes, int n_in,
                              void* d_out, int out_size, void* d_ws, size_t ws_size,
                              hipStream_t stream) {
  (void)in_sizes; (void)n_in; (void)out_size;
  const float* u = (const float*)d_in[0];
  const float* W = (const float*)d_in[1];
  float* out = (float*)d_out;
  const size_t SB = (size_t)Bn * ROW; // 40960
  float* g_s1 = (float*)d_ws;
  float* g_s2 = g_s1 + SB;
  float* g_s3 = g_s2 + SB;
  float* g_v1 = g_s3 + SB;
  float* g_v12 = g_v1 + SB;
  if (ws_size < 5 * SB * sizeof(float)) return;

  k_init<<<120, 256, 0, stream>>>((float4*)g_s1); // zeroes s1,s2,s3 exactly
  k_pass<1><<<1024, 512, 0, stream>>>(u, W, nullptr, g_s1);
  k_sq<0><<<Bn, 256, 0, stream>>>(g_s1, nullptr, g_v1, 0.1f);
  k_pass<2><<<1024, 512, 0, stream>>>(u, W, g_v1, g_s2);
  k_sq<1><<<Bn, 256, 0, stream>>>(g_s2, g_v1, g_v12, 1.0f);
  k_pass<2><<<1024, 512, 0, stream>>>(u, W, g_v12, g_s3);
  k_fin<<<Bn, 256, 0, stream>>>(g_s3, out);
}